// Round 2
// baseline (352.965 us; speedup 1.0000x reference)
//
#include <hip/hip_runtime.h>
#include <stdint.h>

#define NROWS 8192
#define DIM   512
#define JSPLIT 8
#define NPART 16           // JSPLIT * 2 column-half waves
#define JT_PER_BLK 8       // 8192/128/JSPLIT

typedef __attribute__((ext_vector_type(8))) short short8;
typedef __attribute__((ext_vector_type(4))) float f32x4;
typedef unsigned int u32;

// ws layout (bytes)
#define OFF_EBF   0u          // 8192*512*2 = 8388608
#define OFF_CLS   8388608u    // 16*512*4   = 32768
#define OFF_CNT   8421376u    // 16*4 (+pad)= 64
#define OFF_NRM   8421440u    // 8192*4     = 32768
#define OFF_PM    8454208u    // 8192*16*4  = 524288
#define OFF_PL    8978496u    // 8192*16*4  = 524288

__device__ __forceinline__ void gload16(const void* g, void* l) {
  __builtin_amdgcn_global_load_lds((const __attribute__((address_space(1))) u32*)g,
                                   (__attribute__((address_space(3))) u32*)l, 16, 0, 0);
}

__device__ __forceinline__ unsigned short f2bf(float f) {
  u32 u = __float_as_uint(f);
  u32 r = (u + 0x7fffu + ((u >> 16) & 1u)) >> 16;
  return (unsigned short)r;
}

// ---------- kernel 1: fp32 -> bf16 + row norms^2 ----------
__global__ __launch_bounds__(64) void k_prep(const float* __restrict__ E,
                                             unsigned short* __restrict__ Ebf,
                                             float* __restrict__ nrm) {
  const int row = blockIdx.x;
  const int lane = threadIdx.x;  // 64
  const float4* src = (const float4*)(E + row * DIM + lane * 8);
  float4 v0 = src[0], v1 = src[1];
  float ns = v0.x*v0.x + v0.y*v0.y + v0.z*v0.z + v0.w*v0.w
           + v1.x*v1.x + v1.y*v1.y + v1.z*v1.z + v1.w*v1.w;
  u32 p0 = (u32)f2bf(v0.x) | ((u32)f2bf(v0.y) << 16);
  u32 p1 = (u32)f2bf(v0.z) | ((u32)f2bf(v0.w) << 16);
  u32 p2 = (u32)f2bf(v1.x) | ((u32)f2bf(v1.y) << 16);
  u32 p3 = (u32)f2bf(v1.z) | ((u32)f2bf(v1.w) << 16);
  uint4 pk = make_uint4(p0, p1, p2, p3);
  *(uint4*)(Ebf + row * DIM + lane * 8) = pk;
  #pragma unroll
  for (int s = 1; s < 64; s <<= 1) ns += __shfl_xor(ns, s);
  if (lane == 0) nrm[row] = ns;
}

// ---------- kernel 2: class sums (fp32) + class counts ----------
__global__ __launch_bounds__(256) void k_cls(const float* __restrict__ E,
                                             const int* __restrict__ lab,
                                             float* __restrict__ Cls,
                                             int* __restrict__ cnt) {
  __shared__ int lcnt[16];
  const int t = threadIdx.x;
  const int i0 = blockIdx.x * 128;   // 64 blocks x 128 rows
  if (t < 16) lcnt[t] = 0;
  __syncthreads();
  if (t < 128) atomicAdd(&lcnt[lab[i0 + t]], 1);
  float a0[16], a1[16];
  #pragma unroll
  for (int c = 0; c < 16; ++c) { a0[c] = 0.f; a1[c] = 0.f; }
  for (int r = 0; r < 128; ++r) {
    const int lbl = lab[i0 + r];
    const float2 v = *(const float2*)(E + (i0 + r) * DIM + t * 2);
    #pragma unroll
    for (int c = 0; c < 16; ++c) {
      a0[c] += (c == lbl) ? v.x : 0.f;
      a1[c] += (c == lbl) ? v.y : 0.f;
    }
  }
  #pragma unroll
  for (int c = 0; c < 16; ++c) {
    atomicAdd(&Cls[c * DIM + t * 2],     a0[c]);
    atomicAdd(&Cls[c * DIM + t * 2 + 1], a1[c]);
  }
  __syncthreads();
  if (t < 16) atomicAdd(&cnt[t], lcnt[t]);
}

// ---------- kernel 3: flash-style online LSE over S = Ebf*Ebf^T (scaled) ----------
__global__ __launch_bounds__(256) void k_main(const unsigned short* __restrict__ Ebf,
                                              float* __restrict__ partM,
                                              float* __restrict__ partL) {
  __shared__ __align__(16) unsigned short As[128 * 64];
  __shared__ __align__(16) unsigned short Bs[128 * 64];

  const int tid  = threadIdx.x;
  const int lane = tid & 63;
  const int wid  = tid >> 6;
  const int wm   = wid >> 1;   // wave row 0..1
  const int wn   = wid & 1;    // wave col 0..1
  const int g    = lane >> 4;  // 0..3
  const int l15  = lane & 15;

  const int bid    = blockIdx.x;
  const int itile  = bid >> 3;     // 0..63
  const int jsplit = bid & 7;      // 0..7
  const int i0     = itile * 128;

  const float C2 = 14.4269504088896f;  // (1/T) * log2(e)

  float rm[16], rl[16];
  #pragma unroll
  for (int r = 0; r < 16; ++r) { rm[r] = -1e30f; rl[r] = 0.f; }

  // staging geometry: round r, thread tid covers LDS bytes D = r*4096 + tid*16
  int srow[4], selem[4];
  #pragma unroll
  for (int r = 0; r < 4; ++r) {
    const int D   = r * 4096 + tid * 16;
    const int row = D >> 7;             // 0..127 (row stride 128B = 64 bf16)
    const int cb  = (D >> 4) & 7;       // 16B chunk within row
    const int cs  = cb ^ (row & 7);     // pre-swizzled source chunk
    srow[r]  = row;
    selem[r] = cs * 8;                  // bf16 elements
  }

  for (int jt = 0; jt < JT_PER_BLK; ++jt) {
    const int j0 = (jsplit * JT_PER_BLK + jt) * 128;

    f32x4 acc[4][4];
    #pragma unroll
    for (int a = 0; a < 4; ++a)
      #pragma unroll
      for (int b = 0; b < 4; ++b) {
        f32x4 z = {0.f, 0.f, 0.f, 0.f};
        acc[a][b] = z;
      }

    for (int kc = 0; kc < 8; ++kc) {
      #pragma unroll
      for (int r = 0; r < 4; ++r)
        gload16(Ebf + (i0 + srow[r]) * DIM + kc * 64 + selem[r], &As[r * 2048 + tid * 8]);
      #pragma unroll
      for (int r = 0; r < 4; ++r)
        gload16(Ebf + (j0 + srow[r]) * DIM + kc * 64 + selem[r], &Bs[r * 2048 + tid * 8]);
      __syncthreads();   // drains vmcnt(0): LDS tiles ready

      #pragma unroll
      for (int ks = 0; ks < 2; ++ks) {
        const int x = ((ks << 2) | g) ^ (l15 & 7);
        short8 av[4], bv[4];
        #pragma unroll
        for (int mf = 0; mf < 4; ++mf)
          av[mf] = *(const short8*)&As[(wm * 64 + mf * 16 + l15) * 64 + x * 8];
        #pragma unroll
        for (int nf = 0; nf < 4; ++nf)
          bv[nf] = *(const short8*)&Bs[(wn * 64 + nf * 16 + l15) * 64 + x * 8];
        #pragma unroll
        for (int mf = 0; mf < 4; ++mf)
          #pragma unroll
          for (int nf = 0; nf < 4; ++nf)
            acc[mf][nf] = __builtin_amdgcn_mfma_f32_16x16x32_bf16(av[mf], bv[nf], acc[mf][nf], 0, 0, 0);
      }
      __syncthreads();   // safe to overwrite LDS next chunk
    }

    // epilogue: online base-2 logsumexp update for this wave's 64 columns
    const bool diagt = ((jsplit * JT_PER_BLK + jt) == itile) && (wm == wn);
    #pragma unroll
    for (int mf = 0; mf < 4; ++mf) {
      #pragma unroll
      for (int reg = 0; reg < 4; ++reg) {
        const int r16 = mf * 4 + reg;
        float v0 = acc[mf][0][reg];
        float v1 = acc[mf][1][reg];
        float v2 = acc[mf][2][reg];
        float v3 = acc[mf][3][reg];
        if (diagt) {
          const int rr = mf * 16 + g * 4 + reg;   // row within 64x64 wave tile
          v0 = (rr == (l15))      ? -1e30f : v0;
          v1 = (rr == (16 + l15)) ? -1e30f : v1;
          v2 = (rr == (32 + l15)) ? -1e30f : v2;
          v3 = (rr == (48 + l15)) ? -1e30f : v3;
        }
        float tmax = fmaxf(fmaxf(v0, v1), fmaxf(v2, v3));
        #pragma unroll
        for (int s = 1; s < 16; s <<= 1) tmax = fmaxf(tmax, __shfl_xor(tmax, s));
        const float mu = fmaxf(rm[r16], tmax * C2);
        float p = exp2f(v0 * C2 - mu) + exp2f(v1 * C2 - mu)
                + exp2f(v2 * C2 - mu) + exp2f(v3 * C2 - mu);
        #pragma unroll
        for (int s = 1; s < 16; s <<= 1) p += __shfl_xor(p, s);
        rl[r16] = rl[r16] * exp2f(rm[r16] - mu) + p;
        rm[r16] = mu;
      }
    }
  }

  // each (jsplit, wn) pair owns a distinct partial slot: no clobber between
  // the two waves that share the same rows but different column halves
  if (l15 == 0) {
    const int slot = jsplit * 2 + wn;
    #pragma unroll
    for (int mf = 0; mf < 4; ++mf)
      #pragma unroll
      for (int reg = 0; reg < 4; ++reg) {
        const int row = i0 + wm * 64 + mf * 16 + g * 4 + reg;
        partM[row * NPART + slot] = rm[mf * 4 + reg];
        partL[row * NPART + slot] = rl[mf * 4 + reg];
      }
  }
}

// ---------- kernel 4: merge partials + positive term + loss ----------
__global__ __launch_bounds__(256) void k_merge(const float* __restrict__ E,
                                               const int* __restrict__ lab,
                                               const float* __restrict__ nrm,
                                               const float* __restrict__ partM,
                                               const float* __restrict__ partL,
                                               const float* __restrict__ Cls,
                                               const int* __restrict__ cnt,
                                               float* __restrict__ out) {
  const int tid = threadIdx.x;
  const int lane = tid & 63;
  const int wid = tid >> 6;
  const int row = blockIdx.x * 4 + wid;
  const int lbl = lab[row];
  const float4* e = (const float4*)(E + row * DIM + lane * 8);
  const float4* c = (const float4*)(Cls + lbl * DIM + lane * 8);
  float4 e0 = e[0], e1 = e[1], c0 = c[0], c1 = c[1];
  float dp = e0.x*c0.x + e0.y*c0.y + e0.z*c0.z + e0.w*c0.w
           + e1.x*c1.x + e1.y*c1.y + e1.z*c1.z + e1.w*c1.w;
  #pragma unroll
  for (int s = 1; s < 64; s <<= 1) dp += __shfl_xor(dp, s);
  if (lane == 0) {
    float M = -1e30f;
    #pragma unroll
    for (int p = 0; p < NPART; ++p) M = fmaxf(M, partM[row * NPART + p]);
    float L = 0.f;
    #pragma unroll
    for (int p = 0; p < NPART; ++p)
      L += partL[row * NPART + p] * exp2f(partM[row * NPART + p] - M);
    const float lse = 0.6931471805599453f * (M + log2f(L));  // natural-log LSE
    const float pc  = (float)(cnt[lbl] - 1);
    const float pos = (dp - nrm[row]) * 10.0f / pc;
    atomicAdd(out, (pos - lse) * (-0.1f / 8192.0f));
  }
}

extern "C" void kernel_launch(void* const* d_in, const int* in_sizes, int n_in,
                              void* d_out, int out_size, void* d_ws, size_t ws_size,
                              hipStream_t stream) {
  (void)in_sizes; (void)n_in; (void)out_size; (void)ws_size;
  const float* E  = (const float*)d_in[0];
  const int* lab  = (const int*)d_in[1];
  char* ws = (char*)d_ws;
  unsigned short* Ebf = (unsigned short*)(ws + OFF_EBF);
  float* Cls = (float*)(ws + OFF_CLS);
  int*   cnt = (int*)  (ws + OFF_CNT);
  float* nrm = (float*)(ws + OFF_NRM);
  float* pM  = (float*)(ws + OFF_PM);
  float* pL  = (float*)(ws + OFF_PL);

  hipMemsetAsync(ws + OFF_CLS, 0, 32768 + 64, stream);  // Cls + cnt
  hipMemsetAsync(d_out, 0, sizeof(float), stream);

  k_prep <<<NROWS, 64, 0, stream>>>(E, Ebf, nrm);
  k_cls  <<<64, 256, 0, stream>>>(E, lab, Cls, cnt);
  k_main <<<512, 256, 0, stream>>>(Ebf, pM, pL);
  k_merge<<<NROWS / 4, 256, 0, stream>>>(E, lab, nrm, pM, pL, Cls, cnt, (float*)d_out);
}

// Round 3
// 236.994 us; speedup vs baseline: 1.4893x; 1.4893x over previous
//
#include <hip/hip_runtime.h>
#include <stdint.h>

#define NROWS 8192
#define DIM   512
#define JSPLIT 16
#define NPART 32           // JSPLIT * 2 column-half waves
#define JT_PER_BLK 4       // 8192/128/JSPLIT

typedef __attribute__((ext_vector_type(8))) short short8;
typedef __attribute__((ext_vector_type(4))) float f32x4;
typedef unsigned int u32;

// ws layout (bytes)
#define OFF_EBF   0u           // 8192*512*2      = 8388608
#define OFF_CLS   8388608u     // 16*512*4        = 32768
#define OFF_CNT   8421376u     // 64
#define OFF_NRM   8421440u     // 8192*4          = 32768
#define OFF_PM    8454208u     // 8192*32*4       = 1048576
#define OFF_PL    9502784u     // 8192*32*4       = 1048576
#define OFF_CPART 10551360u    // 64*16*512*4     = 2097152
#define OFF_BLK   12648512u    // 2048*4          = 8192

__device__ __forceinline__ void gload16(const void* g, void* l) {
  __builtin_amdgcn_global_load_lds((const __attribute__((address_space(1))) u32*)g,
                                   (__attribute__((address_space(3))) u32*)l, 16, 0, 0);
}

__device__ __forceinline__ unsigned short f2bf(float f) {
  u32 u = __float_as_uint(f);
  u32 r = (u + 0x7fffu + ((u >> 16) & 1u)) >> 16;
  return (unsigned short)r;
}

// ---------- kernel 1: fp32 -> bf16 + row norms^2 ----------
__global__ __launch_bounds__(256) void k_prep(const float* __restrict__ E,
                                              unsigned short* __restrict__ Ebf,
                                              float* __restrict__ nrm) {
  const int tid = threadIdx.x;
  const int lane = tid & 63;
  const int wid = tid >> 6;
  const int row = blockIdx.x * 4 + wid;
  const float4* src = (const float4*)(E + row * DIM + lane * 8);
  float4 v0 = src[0], v1 = src[1];
  float ns = v0.x*v0.x + v0.y*v0.y + v0.z*v0.z + v0.w*v0.w
           + v1.x*v1.x + v1.y*v1.y + v1.z*v1.z + v1.w*v1.w;
  u32 p0 = (u32)f2bf(v0.x) | ((u32)f2bf(v0.y) << 16);
  u32 p1 = (u32)f2bf(v0.z) | ((u32)f2bf(v0.w) << 16);
  u32 p2 = (u32)f2bf(v1.x) | ((u32)f2bf(v1.y) << 16);
  u32 p3 = (u32)f2bf(v1.z) | ((u32)f2bf(v1.w) << 16);
  *(uint4*)(Ebf + row * DIM + lane * 8) = make_uint4(p0, p1, p2, p3);
  #pragma unroll
  for (int s = 1; s < 64; s <<= 1) ns += __shfl_xor(ns, s);
  if (lane == 0) nrm[row] = ns;
}

// ---------- kernel 2: per-block class partial sums (NO global atomics) ----------
__global__ __launch_bounds__(256) void k_cls(const float* __restrict__ E,
                                             const int* __restrict__ lab,
                                             float* __restrict__ Cpart,
                                             int* __restrict__ cnt) {
  __shared__ int lcnt[16];
  const int t = threadIdx.x;          // owns dims {2t, 2t+1}
  const int b = blockIdx.x;           // 64 blocks x 128 rows
  const int i0 = b * 128;
  if (t < 16) lcnt[t] = 0;
  __syncthreads();
  if (t < 128) atomicAdd(&lcnt[lab[i0 + t]], 1);
  float a0[16], a1[16];
  #pragma unroll
  for (int c = 0; c < 16; ++c) { a0[c] = 0.f; a1[c] = 0.f; }
  for (int r = 0; r < 128; ++r) {
    const int lbl = lab[i0 + r];
    const float2 v = *(const float2*)(E + (i0 + r) * DIM + t * 2);
    #pragma unroll
    for (int c = 0; c < 16; ++c) {
      a0[c] += (c == lbl) ? v.x : 0.f;
      a1[c] += (c == lbl) ? v.y : 0.f;
    }
  }
  #pragma unroll
  for (int c = 0; c < 16; ++c)
    *(float2*)(Cpart + b * 8192 + c * DIM + t * 2) = make_float2(a0[c], a1[c]);
  __syncthreads();
  if (t < 16) atomicAdd(&cnt[t], lcnt[t]);
}

// ---------- kernel 2b: reduce class partials ----------
__global__ __launch_bounds__(256) void k_clsred(const float* __restrict__ Cpart,
                                                float* __restrict__ Cls) {
  const int idx = blockIdx.x * 256 + threadIdx.x;   // 32 blocks -> 8192 = 16*512
  float s = 0.f;
  #pragma unroll 8
  for (int b = 0; b < 64; ++b) s += Cpart[b * 8192 + idx];
  Cls[idx] = s;
}

// ---------- kernel 3: flash-style online LSE over S = Ebf*Ebf^T (scaled) ----------
__global__ __launch_bounds__(256) void k_main(const unsigned short* __restrict__ Ebf,
                                              float* __restrict__ partM,
                                              float* __restrict__ partL) {
  __shared__ __align__(16) unsigned short As[128 * 64];
  __shared__ __align__(16) unsigned short Bs[128 * 64];

  const int tid  = threadIdx.x;
  const int lane = tid & 63;
  const int wid  = tid >> 6;
  const int wm   = wid >> 1;   // wave row 0..1
  const int wn   = wid & 1;    // wave col 0..1
  const int g    = lane >> 4;  // 0..3
  const int l15  = lane & 15;

  const int bid    = blockIdx.x;
  const int itile  = bid >> 4;     // 0..63
  const int jsplit = bid & 15;     // 0..15
  const int i0     = itile * 128;

  const float C2 = 14.4269504088896f;  // (1/T) * log2(e)

  // per-lane online (m, l) over this lane's 4-col strip per r16
  float rm[16], rl[16];
  #pragma unroll
  for (int r = 0; r < 16; ++r) { rm[r] = -1e30f; rl[r] = 0.f; }

  // staging geometry: round r, thread tid covers LDS bytes D = r*4096 + tid*16
  int srow[4], selem[4];
  #pragma unroll
  for (int r = 0; r < 4; ++r) {
    const int D   = r * 4096 + tid * 16;
    const int row = D >> 7;             // 0..127 (row stride 128B = 64 bf16)
    const int cb  = (D >> 4) & 7;       // 16B chunk within row
    const int cs  = cb ^ (row & 7);     // pre-swizzled source chunk
    srow[r]  = row;
    selem[r] = cs * 8;                  // bf16 elements
  }

  for (int jt = 0; jt < JT_PER_BLK; ++jt) {
    const int jtg = jsplit * JT_PER_BLK + jt;   // global j-tile 0..63
    const int j0  = jtg * 128;

    f32x4 acc[4][4];
    #pragma unroll
    for (int a = 0; a < 4; ++a)
      #pragma unroll
      for (int b = 0; b < 4; ++b) {
        f32x4 z = {0.f, 0.f, 0.f, 0.f};
        acc[a][b] = z;
      }

    for (int kc = 0; kc < 8; ++kc) {
      #pragma unroll
      for (int r = 0; r < 4; ++r)
        gload16(Ebf + (i0 + srow[r]) * DIM + kc * 64 + selem[r], &As[r * 2048 + tid * 8]);
      #pragma unroll
      for (int r = 0; r < 4; ++r)
        gload16(Ebf + (j0 + srow[r]) * DIM + kc * 64 + selem[r], &Bs[r * 2048 + tid * 8]);
      __syncthreads();   // drains vmcnt(0): LDS tiles ready

      #pragma unroll
      for (int ks = 0; ks < 2; ++ks) {
        const int x = ((ks << 2) | g) ^ (l15 & 7);
        short8 av[4], bv[4];
        #pragma unroll
        for (int mf = 0; mf < 4; ++mf)
          av[mf] = *(const short8*)&As[(wm * 64 + mf * 16 + l15) * 64 + x * 8];
        #pragma unroll
        for (int nf = 0; nf < 4; ++nf)
          bv[nf] = *(const short8*)&Bs[(wn * 64 + nf * 16 + l15) * 64 + x * 8];
        #pragma unroll
        for (int mf = 0; mf < 4; ++mf)
          #pragma unroll
          for (int nf = 0; nf < 4; ++nf)
            acc[mf][nf] = __builtin_amdgcn_mfma_f32_16x16x32_bf16(av[mf], bv[nf], acc[mf][nf], 0, 0, 0);
      }
      __syncthreads();   // safe to overwrite LDS next chunk
    }

    // per-lane online LSE update (no cross-lane work inside the jt loop)
    const bool diagt = (jtg == itile);
    #pragma unroll
    for (int mf = 0; mf < 4; ++mf) {
      #pragma unroll
      for (int reg = 0; reg < 4; ++reg) {
        const int r16 = mf * 4 + reg;
        float v0 = acc[mf][0][reg];
        float v1 = acc[mf][1][reg];
        float v2 = acc[mf][2][reg];
        float v3 = acc[mf][3][reg];
        if (diagt) {
          const int rloc  = wm * 64 + mf * 16 + g * 4 + reg;  // row in 128-tile
          const int cbase = wn * 64 + l15;                    // col base in 128-tile
          v0 = (rloc == cbase)      ? -1e30f : v0;
          v1 = (rloc == cbase + 16) ? -1e30f : v1;
          v2 = (rloc == cbase + 32) ? -1e30f : v2;
          v3 = (rloc == cbase + 48) ? -1e30f : v3;
        }
        const float tmax = fmaxf(fmaxf(v0, v1), fmaxf(v2, v3)) * C2;
        const float mu = fmaxf(rm[r16], tmax);
        const float p = exp2f(__builtin_fmaf(v0, C2, -mu))
                      + exp2f(__builtin_fmaf(v1, C2, -mu))
                      + exp2f(__builtin_fmaf(v2, C2, -mu))
                      + exp2f(__builtin_fmaf(v3, C2, -mu));
        rl[r16] = rl[r16] * exp2f(rm[r16] - mu) + p;
        rm[r16] = mu;
      }
    }
  }

  // one cross-lane merge at the end: combine (m,l) across the 16 lanes of the group
  #pragma unroll
  for (int r16 = 0; r16 < 16; ++r16) {
    float m = rm[r16], l = rl[r16];
    #pragma unroll
    for (int s = 1; s < 16; s <<= 1) {
      const float mo = __shfl_xor(m, s);
      const float lo = __shfl_xor(l, s);
      const float mn = fmaxf(m, mo);
      l = l * exp2f(m - mn) + lo * exp2f(mo - mn);
      m = mn;
    }
    rm[r16] = m; rl[r16] = l;
  }

  if (l15 == 0) {
    const int slot = jsplit * 2 + wn;
    #pragma unroll
    for (int mf = 0; mf < 4; ++mf)
      #pragma unroll
      for (int reg = 0; reg < 4; ++reg) {
        const int row = i0 + wm * 64 + mf * 16 + g * 4 + reg;
        partM[row * NPART + slot] = rm[mf * 4 + reg];
        partL[row * NPART + slot] = rl[mf * 4 + reg];
      }
  }
}

// ---------- kernel 4: merge partials + positive term -> per-block partial ----------
__global__ __launch_bounds__(256) void k_merge(const float* __restrict__ E,
                                               const int* __restrict__ lab,
                                               const float* __restrict__ nrm,
                                               const float* __restrict__ partM,
                                               const float* __restrict__ partL,
                                               const float* __restrict__ Cls,
                                               const int* __restrict__ cnt,
                                               float* __restrict__ blkout) {
  __shared__ float red[4];
  const int tid = threadIdx.x;
  const int lane = tid & 63;
  const int wid = tid >> 6;
  const int row = blockIdx.x * 4 + wid;
  const int lbl = lab[row];
  const float4* e = (const float4*)(E + row * DIM + lane * 8);
  const float4* c = (const float4*)(Cls + lbl * DIM + lane * 8);
  float4 e0 = e[0], e1 = e[1], c0 = c[0], c1 = c[1];
  float dp = e0.x*c0.x + e0.y*c0.y + e0.z*c0.z + e0.w*c0.w
           + e1.x*c1.x + e1.y*c1.y + e1.z*c1.z + e1.w*c1.w;
  #pragma unroll
  for (int s = 1; s < 64; s <<= 1) dp += __shfl_xor(dp, s);

  // parallel merge of the 32 partials on lanes 0..31
  float m = (lane < 32) ? partM[row * NPART + lane] : -1e30f;
  float l = (lane < 32) ? partL[row * NPART + lane] : 0.f;
  #pragma unroll
  for (int s = 1; s < 32; s <<= 1) {
    const float mo = __shfl_xor(m, s);
    const float lo = __shfl_xor(l, s);
    const float mn = fmaxf(m, mo);
    l = l * exp2f(m - mn) + lo * exp2f(mo - mn);
    m = mn;
  }
  if (lane == 0) {
    const float lse = 0.6931471805599453f * (m + log2f(l));  // natural-log LSE
    const float pc  = (float)(cnt[lbl] - 1);
    const float pos = (dp - nrm[row]) * 10.0f / pc;
    red[wid] = pos - lse;
  }
  __syncthreads();
  if (tid == 0) blkout[blockIdx.x] = red[0] + red[1] + red[2] + red[3];
}

// ---------- kernel 5: final reduce (single block, no atomics) ----------
__global__ __launch_bounds__(256) void k_final(const float* __restrict__ blkout,
                                               float* __restrict__ out) {
  __shared__ float w[4];
  const int t = threadIdx.x;
  float s = 0.f;
  #pragma unroll
  for (int k = 0; k < 8; ++k) s += blkout[t + 256 * k];
  #pragma unroll
  for (int sh = 1; sh < 64; sh <<= 1) s += __shfl_xor(s, sh);
  if ((t & 63) == 0) w[t >> 6] = s;
  __syncthreads();
  if (t == 0) out[0] = (w[0] + w[1] + w[2] + w[3]) * (-0.1f / 8192.0f);
}

extern "C" void kernel_launch(void* const* d_in, const int* in_sizes, int n_in,
                              void* d_out, int out_size, void* d_ws, size_t ws_size,
                              hipStream_t stream) {
  (void)in_sizes; (void)n_in; (void)out_size; (void)ws_size;
  const float* E  = (const float*)d_in[0];
  const int* lab  = (const int*)d_in[1];
  char* ws = (char*)d_ws;
  unsigned short* Ebf = (unsigned short*)(ws + OFF_EBF);
  float* Cls  = (float*)(ws + OFF_CLS);
  int*   cnt  = (int*)  (ws + OFF_CNT);
  float* nrm  = (float*)(ws + OFF_NRM);
  float* pM   = (float*)(ws + OFF_PM);
  float* pL   = (float*)(ws + OFF_PL);
  float* Cprt = (float*)(ws + OFF_CPART);
  float* blk  = (float*)(ws + OFF_BLK);

  hipMemsetAsync(ws + OFF_CNT, 0, 64, stream);   // cnt only

  k_prep  <<<NROWS / 4, 256, 0, stream>>>(E, Ebf, nrm);
  k_cls   <<<64, 256, 0, stream>>>(E, lab, Cprt, cnt);
  k_clsred<<<32, 256, 0, stream>>>(Cprt, Cls);
  k_main  <<<64 * JSPLIT, 256, 0, stream>>>(Ebf, pM, pL);
  k_merge <<<NROWS / 4, 256, 0, stream>>>(E, lab, nrm, pM, pL, Cls, cnt, blk);
  k_final <<<1, 256, 0, stream>>>(blk, (float*)d_out);
}

// Round 4
// 222.020 us; speedup vs baseline: 1.5898x; 1.0674x over previous
//
#include <hip/hip_runtime.h>
#include <stdint.h>

#define NROWS 8192
#define DIM   512
#define JSPLIT 16
#define NPART 32           // JSPLIT * 2 column-half waves
#define JT_PER_BLK 4       // 8192/128/JSPLIT
#define NSTEP 32           // JT_PER_BLK * 8 kc-steps

typedef __attribute__((ext_vector_type(8))) short short8;
typedef __attribute__((ext_vector_type(4))) float f32x4;
typedef unsigned int u32;

// ws layout (bytes). CPART shares space with PM/PL (disjoint lifetimes:
// CPART is dead after k_clsred; PM/PL written only by k_main afterwards).
#define OFF_EBF   0u           // 8192*512*2 = 8388608
#define OFF_X     8388608u     // max(CPART 8 MB, PM 1 MB + PL 1 MB)
#define OFF_PM    8388608u
#define OFF_PL    9437184u
#define OFF_CLS   16777216u    // 16*512*4 = 32768
#define OFF_CNT   16809984u    // 64
#define OFF_NRM   16810048u    // 8192*4 = 32768
#define OFF_BLK   16842816u    // 2048*4 = 8192

__device__ __forceinline__ void gload16(const void* g, void* l) {
  __builtin_amdgcn_global_load_lds((const __attribute__((address_space(1))) u32*)g,
                                   (__attribute__((address_space(3))) u32*)l, 16, 0, 0);
}

__device__ __forceinline__ unsigned short f2bf(float f) {
  u32 u = __float_as_uint(f);
  u32 r = (u + 0x7fffu + ((u >> 16) & 1u)) >> 16;
  return (unsigned short)r;
}

// ---------- kernel 1: fp32 -> bf16 + row norms^2 ----------
__global__ __launch_bounds__(256) void k_prep(const float* __restrict__ E,
                                              unsigned short* __restrict__ Ebf,
                                              float* __restrict__ nrm) {
  const int tid = threadIdx.x;
  const int lane = tid & 63;
  const int wid = tid >> 6;
  const int row = blockIdx.x * 4 + wid;
  const float4* src = (const float4*)(E + row * DIM + lane * 8);
  float4 v0 = src[0], v1 = src[1];
  float ns = v0.x*v0.x + v0.y*v0.y + v0.z*v0.z + v0.w*v0.w
           + v1.x*v1.x + v1.y*v1.y + v1.z*v1.z + v1.w*v1.w;
  u32 p0 = (u32)f2bf(v0.x) | ((u32)f2bf(v0.y) << 16);
  u32 p1 = (u32)f2bf(v0.z) | ((u32)f2bf(v0.w) << 16);
  u32 p2 = (u32)f2bf(v1.x) | ((u32)f2bf(v1.y) << 16);
  u32 p3 = (u32)f2bf(v1.z) | ((u32)f2bf(v1.w) << 16);
  *(uint4*)(Ebf + row * DIM + lane * 8) = make_uint4(p0, p1, p2, p3);
  #pragma unroll
  for (int s = 1; s < 64; s <<= 1) ns += __shfl_xor(ns, s);
  if (lane == 0) nrm[row] = ns;
}

// ---------- kernel 2: per-block class partial sums (256 blocks x 32 rows) ----------
__global__ __launch_bounds__(256) void k_cls(const float* __restrict__ E,
                                             const int* __restrict__ lab,
                                             float* __restrict__ Cpart,
                                             int* __restrict__ cnt) {
  __shared__ int lcnt[16];
  const int t = threadIdx.x;          // owns dims {2t, 2t+1}
  const int b = blockIdx.x;           // 256 blocks x 32 rows
  const int i0 = b * 32;
  if (t < 16) lcnt[t] = 0;
  __syncthreads();
  if (t < 32) atomicAdd(&lcnt[lab[i0 + t]], 1);
  float a0[16], a1[16];
  #pragma unroll
  for (int c = 0; c < 16; ++c) { a0[c] = 0.f; a1[c] = 0.f; }
  for (int r = 0; r < 32; ++r) {
    const int lbl = lab[i0 + r];
    const float2 v = *(const float2*)(E + (i0 + r) * DIM + t * 2);
    #pragma unroll
    for (int c = 0; c < 16; ++c) {
      a0[c] += (c == lbl) ? v.x : 0.f;
      a1[c] += (c == lbl) ? v.y : 0.f;
    }
  }
  #pragma unroll
  for (int c = 0; c < 16; ++c)
    *(float2*)(Cpart + b * 8192 + c * DIM + t * 2) = make_float2(a0[c], a1[c]);
  __syncthreads();
  if (t < 16) atomicAdd(&cnt[t], lcnt[t]);
}

// ---------- kernel 2b: reduce class partials ----------
__global__ __launch_bounds__(256) void k_clsred(const float* __restrict__ Cpart,
                                                float* __restrict__ Cls) {
  const int idx = blockIdx.x * 256 + threadIdx.x;   // 32 blocks -> 8192 = 16*512
  float s = 0.f;
  #pragma unroll 8
  for (int b = 0; b < 256; ++b) s += Cpart[b * 8192 + idx];
  Cls[idx] = s;
}

// ---------- kernel 3: flash-style online LSE, 2-phase dbuf + counted vmcnt ----------
__global__ __launch_bounds__(256) void k_main(const unsigned short* __restrict__ Ebf,
                                              float* __restrict__ partM,
                                              float* __restrict__ partL) {
  __shared__ __align__(16) unsigned short As[2][128 * 64];
  __shared__ __align__(16) unsigned short Bs[2][128 * 64];

  const int tid  = threadIdx.x;
  const int lane = tid & 63;
  const int wid  = tid >> 6;
  const int wm   = wid >> 1;   // wave row 0..1
  const int wn   = wid & 1;    // wave col 0..1
  const int g    = lane >> 4;  // 0..3
  const int l15  = lane & 15;

  const int bid    = blockIdx.x;
  const int itile  = bid >> 4;     // 0..63
  const int jsplit = bid & 15;     // 0..15
  const int i0     = itile * 128;

  const float C2 = 14.4269504088896f;  // (1/T) * log2(e)

  float rm[16], rl[16];
  #pragma unroll
  for (int r = 0; r < 16; ++r) { rm[r] = -1e30f; rl[r] = 0.f; }

  // staging geometry: round r, thread tid covers LDS bytes D = r*4096 + tid*16
  int srow[4], selem[4];
  #pragma unroll
  for (int r = 0; r < 4; ++r) {
    const int D   = r * 4096 + tid * 16;
    const int row = D >> 7;             // 0..127 (row stride 128B = 64 bf16)
    const int cb  = (D >> 4) & 7;       // 16B chunk within row
    const int cs  = cb ^ (row & 7);     // pre-swizzled source chunk
    srow[r]  = row;
    selem[r] = cs * 8;                  // bf16 elements
  }

#define STAGE(B, KC, J0)                                                          \
  do {                                                                            \
    _Pragma("unroll")                                                             \
    for (int r = 0; r < 4; ++r) {                                                 \
      gload16(Ebf + (i0 + srow[r]) * DIM + (KC) * 64 + selem[r],                  \
              &As[B][r * 2048 + tid * 8]);                                        \
      gload16(Ebf + ((J0) + srow[r]) * DIM + (KC) * 64 + selem[r],                \
              &Bs[B][r * 2048 + tid * 8]);                                        \
    }                                                                             \
  } while (0)

  f32x4 acc[4][4];
  int cur = 0;
  // prologue: stage step 0 (jt=0, kc=0)
  STAGE(0, 0, jsplit * JT_PER_BLK * 128);

  for (int step = 0; step < NSTEP; ++step) {
    const int jt = step >> 3;
    const int kc = step & 7;
    const int jtg = jsplit * JT_PER_BLK + jt;

    // issue next tile's loads into the other buffer, then wait only for the
    // CURRENT tile's 8 loads (counted vmcnt — next 8 stay in flight)
    if (step + 1 < NSTEP) {
      const int nstep = step + 1;
      const int nkc = nstep & 7;
      const int nj0 = (jsplit * JT_PER_BLK + (nstep >> 3)) * 128;
      STAGE(cur ^ 1, nkc, nj0);
      asm volatile("s_waitcnt vmcnt(8)" ::: "memory");
    } else {
      asm volatile("s_waitcnt vmcnt(0)" ::: "memory");
    }
    __builtin_amdgcn_s_barrier();   // all waves: buf[cur] fully landed

    if (kc == 0) {
      #pragma unroll
      for (int a = 0; a < 4; ++a)
        #pragma unroll
        for (int b = 0; b < 4; ++b) {
          f32x4 z = {0.f, 0.f, 0.f, 0.f};
          acc[a][b] = z;
        }
    }

    #pragma unroll
    for (int ks = 0; ks < 2; ++ks) {
      const int x = ((ks << 2) | g) ^ (l15 & 7);
      short8 av[4], bv[4];
      #pragma unroll
      for (int mf = 0; mf < 4; ++mf)
        av[mf] = *(const short8*)&As[cur][(wm * 64 + mf * 16 + l15) * 64 + x * 8];
      #pragma unroll
      for (int nf = 0; nf < 4; ++nf)
        bv[nf] = *(const short8*)&Bs[cur][(wn * 64 + nf * 16 + l15) * 64 + x * 8];
      #pragma unroll
      for (int mf = 0; mf < 4; ++mf)
        #pragma unroll
        for (int nf = 0; nf < 4; ++nf)
          acc[mf][nf] = __builtin_amdgcn_mfma_f32_16x16x32_bf16(av[mf], bv[nf], acc[mf][nf], 0, 0, 0);
    }
    __builtin_amdgcn_s_barrier();   // all waves done reading buf[cur]

    if (kc == 7) {
      // per-lane online LSE update (register-only; overlaps others' staging)
      const bool diagt = (jtg == itile);
      #pragma unroll
      for (int mf = 0; mf < 4; ++mf) {
        #pragma unroll
        for (int reg = 0; reg < 4; ++reg) {
          const int r16 = mf * 4 + reg;
          float v0 = acc[mf][0][reg];
          float v1 = acc[mf][1][reg];
          float v2 = acc[mf][2][reg];
          float v3 = acc[mf][3][reg];
          if (diagt) {
            const int rloc  = wm * 64 + mf * 16 + g * 4 + reg;  // row in 128-tile
            const int cbase = wn * 64 + l15;                    // col base in 128-tile
            v0 = (rloc == cbase)      ? -1e30f : v0;
            v1 = (rloc == cbase + 16) ? -1e30f : v1;
            v2 = (rloc == cbase + 32) ? -1e30f : v2;
            v3 = (rloc == cbase + 48) ? -1e30f : v3;
          }
          const float tmax = fmaxf(fmaxf(v0, v1), fmaxf(v2, v3)) * C2;
          const float mu = fmaxf(rm[r16], tmax);
          const float p = exp2f(__builtin_fmaf(v0, C2, -mu))
                        + exp2f(__builtin_fmaf(v1, C2, -mu))
                        + exp2f(__builtin_fmaf(v2, C2, -mu))
                        + exp2f(__builtin_fmaf(v3, C2, -mu));
          rl[r16] = rl[r16] * exp2f(rm[r16] - mu) + p;
          rm[r16] = mu;
        }
      }
    }
    cur ^= 1;
  }
#undef STAGE

  // one cross-lane merge at the end: combine (m,l) across the 16 lanes of the group
  #pragma unroll
  for (int r16 = 0; r16 < 16; ++r16) {
    float m = rm[r16], l = rl[r16];
    #pragma unroll
    for (int s = 1; s < 16; s <<= 1) {
      const float mo = __shfl_xor(m, s);
      const float lo = __shfl_xor(l, s);
      const float mn = fmaxf(m, mo);
      l = l * exp2f(m - mn) + lo * exp2f(mo - mn);
      m = mn;
    }
    rm[r16] = m; rl[r16] = l;
  }

  if (l15 == 0) {
    const int slot = jsplit * 2 + wn;
    #pragma unroll
    for (int mf = 0; mf < 4; ++mf)
      #pragma unroll
      for (int reg = 0; reg < 4; ++reg) {
        const int row = i0 + wm * 64 + mf * 16 + g * 4 + reg;
        partM[row * NPART + slot] = rm[mf * 4 + reg];
        partL[row * NPART + slot] = rl[mf * 4 + reg];
      }
  }
}

// ---------- kernel 4: merge partials + nrm-part of positive term ----------
__global__ __launch_bounds__(256) void k_merge(const int* __restrict__ lab,
                                               const float* __restrict__ nrm,
                                               const float* __restrict__ partM,
                                               const float* __restrict__ partL,
                                               const int* __restrict__ cnt,
                                               float* __restrict__ blkout) {
  __shared__ float red[4];
  const int tid = threadIdx.x;
  const int lane = tid & 63;
  const int wid = tid >> 6;
  const int row = blockIdx.x * 4 + wid;

  // parallel merge of the 32 partials on lanes 0..31
  float m = (lane < 32) ? partM[row * NPART + lane] : -1e30f;
  float l = (lane < 32) ? partL[row * NPART + lane] : 0.f;
  #pragma unroll
  for (int s = 1; s < 32; s <<= 1) {
    const float mo = __shfl_xor(m, s);
    const float lo = __shfl_xor(l, s);
    const float mn = fmaxf(m, mo);
    l = l * exp2f(m - mn) + lo * exp2f(mo - mn);
    m = mn;
  }
  if (lane == 0) {
    const float lse = 0.6931471805599453f * (m + log2f(l));  // natural-log LSE
    const int lbl = lab[row];
    const float pc = (float)(cnt[lbl] - 1);
    red[wid] = -nrm[row] * 10.0f / pc - lse;   // pos dot-part handled in k_final
  }
  __syncthreads();
  if (tid == 0) blkout[blockIdx.x] = red[0] + red[1] + red[2] + red[3];
}

// ---------- kernel 5: final reduce + class-norm positive part ----------
__global__ __launch_bounds__(256) void k_final(const float* __restrict__ blkout,
                                               const float* __restrict__ Cls,
                                               const int* __restrict__ cnt,
                                               float* __restrict__ out) {
  __shared__ float w[4];
  const int t = threadIdx.x;
  float s = 0.f;
  #pragma unroll
  for (int k = 0; k < 8; ++k) s += blkout[t + 256 * k];
  // sum_k 10*|c_k|^2/(cnt_k-1): thread t covers dims {2t, 2t+1} of every class
  #pragma unroll
  for (int c = 0; c < 16; ++c) {
    const float2 v = *(const float2*)(Cls + c * DIM + t * 2);
    const float wc = 10.0f / (float)(cnt[c] - 1);
    s += wc * (v.x * v.x + v.y * v.y);
  }
  #pragma unroll
  for (int sh = 1; sh < 64; sh <<= 1) s += __shfl_xor(s, sh);
  if ((t & 63) == 0) w[t >> 6] = s;
  __syncthreads();
  if (t == 0) out[0] = (w[0] + w[1] + w[2] + w[3]) * (-0.1f / 8192.0f);
}

extern "C" void kernel_launch(void* const* d_in, const int* in_sizes, int n_in,
                              void* d_out, int out_size, void* d_ws, size_t ws_size,
                              hipStream_t stream) {
  (void)in_sizes; (void)n_in; (void)out_size; (void)ws_size;
  const float* E  = (const float*)d_in[0];
  const int* lab  = (const int*)d_in[1];
  char* ws = (char*)d_ws;
  unsigned short* Ebf = (unsigned short*)(ws + OFF_EBF);
  float* Cprt = (float*)(ws + OFF_X);
  float* pM   = (float*)(ws + OFF_PM);
  float* pL   = (float*)(ws + OFF_PL);
  float* Cls  = (float*)(ws + OFF_CLS);
  int*   cnt  = (int*)  (ws + OFF_CNT);
  float* nrm  = (float*)(ws + OFF_NRM);
  float* blk  = (float*)(ws + OFF_BLK);

  hipMemsetAsync(ws + OFF_CNT, 0, 64, stream);   // cnt only

  k_prep  <<<NROWS / 4, 256, 0, stream>>>(E, Ebf, nrm);
  k_cls   <<<256, 256, 0, stream>>>(E, lab, Cprt, cnt);
  k_clsred<<<32, 256, 0, stream>>>(Cprt, Cls);
  k_main  <<<64 * JSPLIT, 256, 0, stream>>>(Ebf, pM, pL);
  k_merge <<<NROWS / 4, 256, 0, stream>>>(lab, nrm, pM, pL, cnt, blk);
  k_final <<<1, 256, 0, stream>>>(blk, Cls, cnt, (float*)d_out);
}